// Round 1
// baseline (342.368 us; speedup 1.0000x reference)
//
#include <hip/hip_runtime.h>
#include <hip/hip_bf16.h>

typedef __bf16 bf16;
typedef __bf16 bf16x8 __attribute__((ext_vector_type(8)));
typedef float f32x4 __attribute__((ext_vector_type(4)));

#define B_ 4
#define NE_ 1536
#define NR_ 512
#define N_ 2048
#define D_ 128
#define H_ 4
#define DH_ 32
#define P_ 2
#define M_ (B_*N_)      // 8192 rows total
#define NW_ (N_/32)     // 64 mask words per row

__device__ __forceinline__ f32x4 mfma16(bf16x8 a, bf16x8 b, f32x4 c) {
    return __builtin_amdgcn_mfma_f32_16x16x32_bf16(a, b, c, 0, 0, 0);
}

// ---------------- vgraph build: concat(vents, renc_w[rels]) -> f32 + bf16 ----
__global__ void k_vgraph(const float* __restrict__ vents, const int* __restrict__ rels,
                         const float* __restrict__ renc, float* __restrict__ vf,
                         bf16* __restrict__ vb) {
    int idx = blockIdx.x * 256 + threadIdx.x;
    if (idx >= B_ * N_ * D_) return;
    int d = idx & (D_ - 1);
    int n = (idx >> 7) & (N_ - 1);
    int b = idx >> 18;                       // 2048*128 = 2^18
    float v;
    if (n < NE_) v = vents[((size_t)(b * NE_ + n)) * D_ + d];
    else         v = renc[(size_t)rels[b * NR_ + (n - NE_)] * D_ + d];
    vf[idx] = v;
    vb[idx] = (bf16)v;
}

// ---------------- adj -> bitmask (bit=1 means allowed, adj!=0) --------------
__global__ void k_mask(const int* __restrict__ adj, unsigned int* __restrict__ mw) {
    int idx = blockIdx.x * 256 + threadIdx.x;   // word index
    if (idx >= B_ * N_ * NW_) return;
    const int4* a = (const int4*)(adj + (size_t)idx * 32);
    unsigned int w = 0;
#pragma unroll
    for (int q = 0; q < 8; ++q) {
        int4 t = a[q];
        w |= (t.x != 0 ? 1u : 0u) << (q * 4 + 0);
        w |= (t.y != 0 ? 1u : 0u) << (q * 4 + 1);
        w |= (t.z != 0 ? 1u : 0u) << (q * 4 + 2);
        w |= (t.w != 0 ? 1u : 0u) << (q * 4 + 3);
    }
    mw[idx] = w;
}

// ---------------- weight prep: f32 [in,out] -> bf16 [out,in], + bias concat --
__global__ void k_prep(const float* __restrict__ Wq, const float* __restrict__ Wk,
                       const float* __restrict__ Wv, const float* __restrict__ Wo,
                       const float* __restrict__ l1w, const float* __restrict__ l2w,
                       const float* __restrict__ bq, const float* __restrict__ bk,
                       const float* __restrict__ bv,
                       bf16* __restrict__ wqkvT, float* __restrict__ bqkv,
                       bf16* __restrict__ woT, bf16* __restrict__ l1T,
                       bf16* __restrict__ l2T) {
    const int PER = 3 * 16384 + 16384 + 65536 + 65536 + 384;  // 196992
    int idx = blockIdx.x * 256 + threadIdx.x;
    if (idx >= P_ * PER) return;
    int p = idx / PER;
    int r = idx % PER;
    if (r < 3 * 16384) {
        int which = r / 16384, e = r % 16384;
        int o = e >> 7, i = e & 127;
        const float* W = which == 0 ? Wq : (which == 1 ? Wk : Wv);
        wqkvT[(size_t)(p * 384 + which * 128 + o) * 128 + i] = (bf16)W[(size_t)(p * 128 + i) * 128 + o];
    } else if ((r -= 3 * 16384) < 16384) {
        int o = r >> 7, i = r & 127;
        woT[(size_t)(p * 128 + o) * 128 + i] = (bf16)Wo[(size_t)(p * 128 + i) * 128 + o];
    } else if ((r -= 16384) < 65536) {
        int o = r >> 7, i = r & 127;          // o<512, i<128
        l1T[(size_t)(p * 512 + o) * 128 + i] = (bf16)l1w[(size_t)(p * 128 + i) * 512 + o];
    } else if ((r -= 65536) < 65536) {
        int o = r >> 9, i = r & 511;          // o<128, i<512
        l2T[(size_t)(p * 128 + o) * 512 + i] = (bf16)l2w[(size_t)(p * 512 + i) * 128 + o];
    } else {
        r -= 65536;                            // r < 384
        float v = r < 128 ? bq[p * 128 + r]
                          : (r < 256 ? bk[p * 128 + r - 128] : bv[p * 128 + r - 256]);
        bqkv[p * 384 + r] = v;
    }
}

// ---------------- generic MFMA GEMM: Y = act(X[M,K] @ W[K,Nc] + bias) -------
// WT is [Nc,K] bf16 (transposed weights). One wave per block -> 64x64 tile.
// EPI: 0 = f32 out; 1 = bf16 out with PReLU; 2 = QKV split epilogue
template <int K, int EPI>
__global__ void k_gemm(const bf16* __restrict__ X, const bf16* __restrict__ WT,
                       const float* __restrict__ bias, const float* __restrict__ pa,
                       float* __restrict__ outF, bf16* __restrict__ outB,
                       bf16* __restrict__ Kout, bf16* __restrict__ VTout, int Nc) {
    int lane = threadIdx.x;
    int m0 = blockIdx.x * 64;
    int n0 = blockIdx.y * 64;
    int lr = lane & 15, lg = lane >> 4;
    f32x4 acc[4][4];
#pragma unroll
    for (int mi = 0; mi < 4; ++mi)
#pragma unroll
        for (int ni = 0; ni < 4; ++ni)
            acc[mi][ni] = f32x4{0.f, 0.f, 0.f, 0.f};

    for (int k0 = 0; k0 < K; k0 += 32) {
        bf16x8 a[4], bb[4];
#pragma unroll
        for (int mi = 0; mi < 4; ++mi)
            a[mi] = *(const bf16x8*)(X + (size_t)(m0 + mi * 16 + lr) * K + k0 + lg * 8);
#pragma unroll
        for (int ni = 0; ni < 4; ++ni)
            bb[ni] = *(const bf16x8*)(WT + (size_t)(n0 + ni * 16 + lr) * K + k0 + lg * 8);
#pragma unroll
        for (int mi = 0; mi < 4; ++mi)
#pragma unroll
            for (int ni = 0; ni < 4; ++ni)
                acc[mi][ni] = mfma16(a[mi], bb[ni], acc[mi][ni]);
    }
#pragma unroll
    for (int mi = 0; mi < 4; ++mi) {
#pragma unroll
        for (int ni = 0; ni < 4; ++ni) {
            int col = n0 + ni * 16 + lr;
            float bs = bias[col];
#pragma unroll
            for (int r = 0; r < 4; ++r) {
                int row = m0 + mi * 16 + lg * 4 + r;
                float v = acc[mi][ni][r] + bs;
                if (EPI == 0) {
                    outF[(size_t)row * Nc + col] = v;
                } else if (EPI == 1) {
                    v = v >= 0.f ? v : pa[col] * v;
                    outB[(size_t)row * Nc + col] = (bf16)v;
                } else {
                    int b = row >> 11, nn = row & (N_ - 1);
                    if (col < 128) {
                        outB[(size_t)row * D_ + col] = (bf16)v;              // Q [B,N,D]
                    } else if (col < 256) {
                        Kout[(size_t)row * D_ + (col - 128)] = (bf16)v;      // K [B,N,D]
                    } else {
                        int d = col - 256, h = d >> 5, dh = d & 31;
                        VTout[((size_t)(b * H_ + h) * DH_ + dh) * N_ + nn] = (bf16)v;  // VT [B,H,DH,N]
                    }
                }
            }
        }
    }
}

// ---------------- fused flash attention with adjacency mask -----------------
// grid (N/128, B*H), block 256 (4 waves); each wave: 32 q-rows.
__global__ __launch_bounds__(256) void k_attn(
    const bf16* __restrict__ Q, const bf16* __restrict__ Kt,
    const bf16* __restrict__ VT, const unsigned int* __restrict__ mw,
    bf16* __restrict__ O) {
    __shared__ __align__(16) bf16 plds[4][32 * 40];   // per-wave P tile, stride 40 pads banks
    int wid = threadIdx.x >> 6;
    int lane = threadIdx.x & 63;
    int lr = lane & 15, lg = lane >> 4;
    int bh = blockIdx.y;
    int b = bh >> 2, h = bh & 3;
    int q0 = blockIdx.x * 128 + wid * 32;
    const size_t bnD = (size_t)b * N_ * D_;

    bf16x8 qf[2];
#pragma unroll
    for (int qs = 0; qs < 2; ++qs)
        qf[qs] = *(const bf16x8*)(Q + bnD + (size_t)(q0 + qs * 16 + lr) * D_ + h * 32 + lg * 8);

    float mrow[2][4], lrow[2][4];
    f32x4 of[2][2];
#pragma unroll
    for (int qs = 0; qs < 2; ++qs) {
#pragma unroll
        for (int r = 0; r < 4; ++r) { mrow[qs][r] = -INFINITY; lrow[qs][r] = 0.f; }
        of[qs][0] = f32x4{0.f, 0.f, 0.f, 0.f};
        of[qs][1] = f32x4{0.f, 0.f, 0.f, 0.f};
    }
    const float scale = 0.17677669529663687f;    // 1/sqrt(32)
    const unsigned int* mwb = mw + (size_t)b * N_ * NW_;
    bf16* pl = plds[wid];

    for (int ks = 0; ks < N_ / 32; ++ks) {
        bf16x8 kf[2];
#pragma unroll
        for (int t = 0; t < 2; ++t)
            kf[t] = *(const bf16x8*)(Kt + bnD + (size_t)(ks * 32 + t * 16 + lr) * D_ + h * 32 + lg * 8);
        f32x4 s[2][2];
#pragma unroll
        for (int qs = 0; qs < 2; ++qs)
#pragma unroll
            for (int t = 0; t < 2; ++t)
                s[qs][t] = mfma16(qf[qs], kf[t], f32x4{0.f, 0.f, 0.f, 0.f});

#pragma unroll
        for (int qs = 0; qs < 2; ++qs) {
#pragma unroll
            for (int r = 0; r < 4; ++r) {
                int row = q0 + qs * 16 + lg * 4 + r;
                unsigned int w = mwb[(size_t)row * NW_ + ks];
                float s0 = ((w >> lr) & 1u) ? s[qs][0][r] * scale : -1e9f;
                float s1 = ((w >> (16 + lr)) & 1u) ? s[qs][1][r] * scale : -1e9f;
                float tm = fmaxf(s0, s1);
#pragma unroll
                for (int m = 1; m < 16; m <<= 1) tm = fmaxf(tm, __shfl_xor(tm, m, 64));
                float mn = fmaxf(mrow[qs][r], tm);
                float al = __expf(mrow[qs][r] - mn);
                mrow[qs][r] = mn;
                float p0 = __expf(s0 - mn), p1 = __expf(s1 - mn);
                float ps = p0 + p1;
#pragma unroll
                for (int m = 1; m < 16; m <<= 1) ps += __shfl_xor(ps, m, 64);
                lrow[qs][r] = lrow[qs][r] * al + ps;
                of[qs][0][r] *= al;
                of[qs][1][r] *= al;
                int lrw = qs * 16 + lg * 4 + r;
                pl[lrw * 40 + lr] = (bf16)p0;
                pl[lrw * 40 + 16 + lr] = (bf16)p1;
            }
        }
        bf16x8 pa2[2];
#pragma unroll
        for (int qs = 0; qs < 2; ++qs)
            pa2[qs] = *(const bf16x8*)(pl + (qs * 16 + lr) * 40 + lg * 8);
        bf16x8 vf2[2];
#pragma unroll
        for (int d2 = 0; d2 < 2; ++d2)
            vf2[d2] = *(const bf16x8*)(VT + ((size_t)(bh * DH_) + d2 * 16 + lr) * N_ + ks * 32 + lg * 8);
#pragma unroll
        for (int qs = 0; qs < 2; ++qs)
#pragma unroll
            for (int d2 = 0; d2 < 2; ++d2)
                of[qs][d2] = mfma16(pa2[qs], vf2[d2], of[qs][d2]);
    }
#pragma unroll
    for (int qs = 0; qs < 2; ++qs)
#pragma unroll
        for (int d2 = 0; d2 < 2; ++d2)
#pragma unroll
            for (int r = 0; r < 4; ++r) {
                int row = q0 + qs * 16 + lg * 4 + r;
                float v = of[qs][d2][r] / lrow[qs][r];
                O[bnD + (size_t)row * D_ + h * 32 + d2 * 16 + lr] = (bf16)v;
            }
}

// ---------------- LayerNorm (optional residual add): 1 wave per row ---------
__global__ void k_ln(const float* __restrict__ x, const float* __restrict__ res,
                     const float* __restrict__ g, const float* __restrict__ bta,
                     float* __restrict__ outF, bf16* __restrict__ outB) {
    int row = blockIdx.x * 4 + (threadIdx.x >> 6);
    int lane = threadIdx.x & 63;
    const float* xr = x + (size_t)row * D_;
    float2 e = *(const float2*)(xr + lane * 2);
    if (res) {
        float2 rr = *(const float2*)(res + (size_t)row * D_ + lane * 2);
        e.x += rr.x; e.y += rr.y;
    }
    float s = e.x + e.y, sq = e.x * e.x + e.y * e.y;
#pragma unroll
    for (int m = 1; m < 64; m <<= 1) {
        s += __shfl_xor(s, m, 64);
        sq += __shfl_xor(sq, m, 64);
    }
    float mean = s * (1.f / 128.f);
    float var = sq * (1.f / 128.f) - mean * mean;
    float rstd = rsqrtf(var + 1e-5f);
    float o0 = (e.x - mean) * rstd * g[lane * 2] + bta[lane * 2];
    float o1 = (e.y - mean) * rstd * g[lane * 2 + 1] + bta[lane * 2 + 1];
    float2 of2; of2.x = o0; of2.y = o1;
    *(float2*)(outF + (size_t)row * D_ + lane * 2) = of2;
    union { bf16 hh[2]; unsigned int u; } pk;
    pk.hh[0] = (bf16)o0; pk.hh[1] = (bf16)o1;
    *(unsigned int*)(outB + (size_t)row * D_ + lane * 2) = pk.u;
}

// ---------------- final outputs: glob, gents, emask --------------------------
__global__ void k_out(const float* __restrict__ vf, const int* __restrict__ entlens,
                      float* __restrict__ out) {
    int idx = blockIdx.x * 256 + threadIdx.x;
    if (idx < 512) {
        int b = idx >> 7, d = idx & 127;
        out[idx] = vf[((size_t)b * N_ + entlens[b]) * D_ + d];
    } else if (idx < 512 + B_ * N_ * D_) {
        out[idx] = vf[idx - 512];
    } else if (idx < 512 + B_ * N_ * D_ + B_ * N_) {
        out[idx] = 1.0f;
    }
}

extern "C" void kernel_launch(void* const* d_in, const int* in_sizes, int n_in,
                              void* d_out, int out_size, void* d_ws, size_t ws_size,
                              hipStream_t stream) {
    const float* vents = (const float*)d_in[0];
    const int*   rels  = (const int*)d_in[1];
    const int*   adj   = (const int*)d_in[2];
    const int*   entl  = (const int*)d_in[3];
    const float* renc  = (const float*)d_in[4];
    const float* Wq = (const float*)d_in[5];
    const float* bq = (const float*)d_in[6];
    const float* Wk = (const float*)d_in[7];
    const float* bk = (const float*)d_in[8];
    const float* Wv = (const float*)d_in[9];
    const float* bv = (const float*)d_in[10];
    const float* Wo = (const float*)d_in[11];
    const float* bo = (const float*)d_in[12];
    const float* l1w = (const float*)d_in[13];
    const float* l1b = (const float*)d_in[14];
    const float* l2w = (const float*)d_in[15];
    const float* l2b = (const float*)d_in[16];
    const float* lng = (const float*)d_in[17];
    const float* lnb = (const float*)d_in[18];
    const float* pra = (const float*)d_in[19];

    char* w = (char*)d_ws;
    auto alloc = [&](size_t bytes) { char* r = w; w += (bytes + 255) & ~(size_t)255; return r; };
    float* vf    = (float*)alloc((size_t)M_ * D_ * 4);
    bf16*  vb    = (bf16*)alloc((size_t)M_ * D_ * 2);
    unsigned int* mw = (unsigned int*)alloc((size_t)B_ * N_ * NW_ * 4);
    bf16*  wqkvT = (bf16*)alloc((size_t)P_ * 384 * 128 * 2);
    float* bqkv  = (float*)alloc((size_t)P_ * 384 * 4);
    bf16*  woT   = (bf16*)alloc((size_t)P_ * 128 * 128 * 2);
    bf16*  l1T   = (bf16*)alloc((size_t)P_ * 512 * 128 * 2);
    bf16*  l2T   = (bf16*)alloc((size_t)P_ * 128 * 512 * 2);
    bf16*  Qb    = (bf16*)alloc((size_t)M_ * D_ * 2);
    bf16*  Kb    = (bf16*)alloc((size_t)M_ * D_ * 2);
    bf16*  VTb   = (bf16*)alloc((size_t)M_ * D_ * 2);
    bf16*  Ob    = (bf16*)alloc((size_t)M_ * D_ * 2);
    float* Oproj = (float*)alloc((size_t)M_ * D_ * 4);
    float* tf    = (float*)alloc((size_t)M_ * D_ * 4);
    bf16*  tb    = (bf16*)alloc((size_t)M_ * D_ * 2);
    bf16*  h1    = (bf16*)alloc((size_t)M_ * 512 * 2);
    float* q2    = (float*)alloc((size_t)M_ * D_ * 4);

    k_vgraph<<<(M_ * D_ + 255) / 256, 256, 0, stream>>>(vents, rels, renc, vf, vb);
    k_mask<<<(B_ * N_ * NW_ + 255) / 256, 256, 0, stream>>>(adj, mw);
    k_prep<<<(P_ * 196992 + 255) / 256, 256, 0, stream>>>(Wq, Wk, Wv, Wo, l1w, l2w,
                                                          bq, bk, bv, wqkvT, bqkv, woT, l1T, l2T);
    for (int p = 0; p < P_; ++p) {
        k_gemm<128, 2><<<dim3(M_ / 64, 384 / 64), 64, 0, stream>>>(
            vb, wqkvT + (size_t)p * 384 * 128, bqkv + p * 384, nullptr,
            nullptr, Qb, Kb, VTb, 384);
        k_attn<<<dim3(N_ / 128, B_ * H_), 256, 0, stream>>>(Qb, Kb, VTb, mw, Ob);
        k_gemm<128, 0><<<dim3(M_ / 64, 128 / 64), 64, 0, stream>>>(
            Ob, woT + (size_t)p * 128 * 128, bo + p * 128, nullptr,
            Oproj, nullptr, nullptr, nullptr, 128);
        k_ln<<<M_ / 4, 256, 0, stream>>>(Oproj, nullptr, lng + p * 128, lnb + p * 128, tf, tb);
        k_gemm<128, 1><<<dim3(M_ / 64, 512 / 64), 64, 0, stream>>>(
            tb, l1T + (size_t)p * 512 * 128, l1b + p * 512, pra + p * 512,
            nullptr, h1, nullptr, nullptr, 512);
        k_gemm<512, 0><<<dim3(M_ / 64, 128 / 64), 64, 0, stream>>>(
            h1, l2T + (size_t)p * 128 * 512, l2b + p * 128, nullptr,
            q2, nullptr, nullptr, nullptr, 128);
        k_ln<<<M_ / 4, 256, 0, stream>>>(q2, tf, lng + p * 128, lnb + p * 128, vf, vb);
    }
    k_out<<<(512 + M_ * D_ + B_ * N_ + 255) / 256, 256, 0, stream>>>(vf, entl, (float*)d_out);
}

// Round 2
// 262.878 us; speedup vs baseline: 1.3024x; 1.3024x over previous
//
#include <hip/hip_runtime.h>
#include <hip/hip_bf16.h>

typedef __bf16 bf16;
typedef __bf16 bf16x4 __attribute__((ext_vector_type(4)));
typedef __bf16 bf16x8 __attribute__((ext_vector_type(8)));
typedef float f32x4 __attribute__((ext_vector_type(4)));

#define B_ 4
#define NE_ 1536
#define NR_ 512
#define N_ 2048
#define D_ 128
#define H_ 4
#define DH_ 32
#define P_ 2
#define M_ (B_*N_)      // 8192 rows total
#define NW_ (N_/32)     // 64 mask words per row

__device__ __forceinline__ f32x4 mfma16(bf16x8 a, bf16x8 b, f32x4 c) {
    return __builtin_amdgcn_mfma_f32_16x16x32_bf16(a, b, c, 0, 0, 0);
}

// ---------------- vgraph build: concat(vents, renc_w[rels]) -> f32 + bf16 ----
__global__ void k_vgraph(const float* __restrict__ vents, const int* __restrict__ rels,
                         const float* __restrict__ renc, float* __restrict__ vf,
                         bf16* __restrict__ vb) {
    int idx = blockIdx.x * 256 + threadIdx.x;
    if (idx >= B_ * N_ * D_) return;
    int d = idx & (D_ - 1);
    int n = (idx >> 7) & (N_ - 1);
    int b = idx >> 18;                       // 2048*128 = 2^18
    float v;
    if (n < NE_) v = vents[((size_t)(b * NE_ + n)) * D_ + d];
    else         v = renc[(size_t)rels[b * NR_ + (n - NE_)] * D_ + d];
    vf[idx] = v;
    vb[idx] = (bf16)v;
}

// ---------------- adj -> bitmask (bit=1 means allowed, adj!=0) --------------
__global__ void k_mask(const int* __restrict__ adj, unsigned int* __restrict__ mw) {
    int idx = blockIdx.x * 256 + threadIdx.x;   // word index
    if (idx >= B_ * N_ * NW_) return;
    const int4* a = (const int4*)(adj + (size_t)idx * 32);
    unsigned int w = 0;
#pragma unroll
    for (int q = 0; q < 8; ++q) {
        int4 t = a[q];
        w |= (t.x != 0 ? 1u : 0u) << (q * 4 + 0);
        w |= (t.y != 0 ? 1u : 0u) << (q * 4 + 1);
        w |= (t.z != 0 ? 1u : 0u) << (q * 4 + 2);
        w |= (t.w != 0 ? 1u : 0u) << (q * 4 + 3);
    }
    mw[idx] = w;
}

// ---------------- weight prep: f32 [in,out] -> bf16 [out,in], + bias concat --
__global__ void k_prep(const float* __restrict__ Wq, const float* __restrict__ Wk,
                       const float* __restrict__ Wv, const float* __restrict__ Wo,
                       const float* __restrict__ l1w, const float* __restrict__ l2w,
                       const float* __restrict__ bq, const float* __restrict__ bk,
                       const float* __restrict__ bv,
                       bf16* __restrict__ wqkvT, float* __restrict__ bqkv,
                       bf16* __restrict__ woT, bf16* __restrict__ l1T,
                       bf16* __restrict__ l2T) {
    const int PER = 3 * 16384 + 16384 + 65536 + 65536 + 384;  // 196992
    int idx = blockIdx.x * 256 + threadIdx.x;
    if (idx >= P_ * PER) return;
    int p = idx / PER;
    int r = idx % PER;
    if (r < 3 * 16384) {
        int which = r / 16384, e = r % 16384;
        int o = e >> 7, i = e & 127;
        const float* W = which == 0 ? Wq : (which == 1 ? Wk : Wv);
        wqkvT[(size_t)(p * 384 + which * 128 + o) * 128 + i] = (bf16)W[(size_t)(p * 128 + i) * 128 + o];
    } else if ((r -= 3 * 16384) < 16384) {
        int o = r >> 7, i = r & 127;
        woT[(size_t)(p * 128 + o) * 128 + i] = (bf16)Wo[(size_t)(p * 128 + i) * 128 + o];
    } else if ((r -= 16384) < 65536) {
        int o = r >> 7, i = r & 127;          // o<512, i<128
        l1T[(size_t)(p * 512 + o) * 128 + i] = (bf16)l1w[(size_t)(p * 128 + i) * 512 + o];
    } else if ((r -= 65536) < 65536) {
        int o = r >> 9, i = r & 511;          // o<128, i<512
        l2T[(size_t)(p * 128 + o) * 512 + i] = (bf16)l2w[(size_t)(p * 512 + i) * 128 + o];
    } else {
        r -= 65536;                            // r < 384
        float v = r < 128 ? bq[p * 128 + r]
                          : (r < 256 ? bk[p * 128 + r - 128] : bv[p * 128 + r - 256]);
        bqkv[p * 384 + r] = v;
    }
}

// ---------------- generic MFMA GEMM: Y = act(X[M,K] @ W[K,Nc] + bias) -------
// WT is [Nc,K] bf16 (transposed weights). One wave per block -> 64x64 tile.
// EPI: 0 = f32 out; 1 = bf16 out with PReLU; 2 = QKV split epilogue
template <int K, int EPI>
__global__ void k_gemm(const bf16* __restrict__ X, const bf16* __restrict__ WT,
                       const float* __restrict__ bias, const float* __restrict__ pa,
                       float* __restrict__ outF, bf16* __restrict__ outB,
                       bf16* __restrict__ Kout, bf16* __restrict__ VTout, int Nc) {
    int lane = threadIdx.x;
    int m0 = blockIdx.x * 64;
    int n0 = blockIdx.y * 64;
    int lr = lane & 15, lg = lane >> 4;
    f32x4 acc[4][4];
#pragma unroll
    for (int mi = 0; mi < 4; ++mi)
#pragma unroll
        for (int ni = 0; ni < 4; ++ni)
            acc[mi][ni] = f32x4{0.f, 0.f, 0.f, 0.f};

    for (int k0 = 0; k0 < K; k0 += 32) {
        bf16x8 a[4], bb[4];
#pragma unroll
        for (int mi = 0; mi < 4; ++mi)
            a[mi] = *(const bf16x8*)(X + (size_t)(m0 + mi * 16 + lr) * K + k0 + lg * 8);
#pragma unroll
        for (int ni = 0; ni < 4; ++ni)
            bb[ni] = *(const bf16x8*)(WT + (size_t)(n0 + ni * 16 + lr) * K + k0 + lg * 8);
#pragma unroll
        for (int mi = 0; mi < 4; ++mi)
#pragma unroll
            for (int ni = 0; ni < 4; ++ni)
                acc[mi][ni] = mfma16(a[mi], bb[ni], acc[mi][ni]);
    }
#pragma unroll
    for (int mi = 0; mi < 4; ++mi) {
#pragma unroll
        for (int ni = 0; ni < 4; ++ni) {
            int col = n0 + ni * 16 + lr;
            float bs = bias[col];
#pragma unroll
            for (int r = 0; r < 4; ++r) {
                int row = m0 + mi * 16 + lg * 4 + r;
                float v = acc[mi][ni][r] + bs;
                if (EPI == 0) {
                    outF[(size_t)row * Nc + col] = v;
                } else if (EPI == 1) {
                    v = v >= 0.f ? v : pa[col] * v;
                    outB[(size_t)row * Nc + col] = (bf16)v;
                } else {
                    int b = row >> 11, nn = row & (N_ - 1);
                    if (col < 128) {
                        outB[(size_t)row * D_ + col] = (bf16)v;              // Q [B,N,D]
                    } else if (col < 256) {
                        Kout[(size_t)row * D_ + (col - 128)] = (bf16)v;      // K [B,N,D]
                    } else {
                        int d = col - 256, h = d >> 5, dh = d & 31;
                        VTout[((size_t)(b * H_ + h) * DH_ + dh) * N_ + nn] = (bf16)v;  // VT [B,H,DH,N]
                    }
                }
            }
        }
    }
}

// ---------------- fused flash attention, swapped-operand layout -------------
// grid (N/64, B*H), block 256 (4 waves); each wave: 16 q-rows, KVBLK=64.
// S^T = mfma(K,Q): lane holds 16 scores (k-slice) of q-row (lane&15)
// O^T = mfma(VT, P^T): consumes VT [B,H,DH,N] directly.
__global__ __launch_bounds__(256) void k_attn(
    const bf16* __restrict__ Q, const bf16* __restrict__ Kt,
    const bf16* __restrict__ VT, const unsigned int* __restrict__ mw,
    bf16* __restrict__ O) {
    // per-wave P^T tile: 16 q-rows x 64 k, row padded to 72 elems (144B):
    // b64 writes and b128 reads both hit the LDS bandwidth minimum (slot
    // index rotates by 1 per row since 144B = 9 x 16B).
    __shared__ __align__(16) bf16 plds[4][16 * 72];
    int wid = threadIdx.x >> 6;
    int lane = threadIdx.x & 63;
    int lr = lane & 15, lg = lane >> 4;
    int bh = blockIdx.y;
    int b = bh >> 2, h = bh & 3;
    int q = blockIdx.x * 64 + wid * 16 + lr;
    const size_t bnD = (size_t)b * N_ * D_;

    // Q as MFMA B-operand: col = q (lane&15), k-elems = dh (lg*8..+8)
    bf16x8 qf = *(const bf16x8*)(Q + bnD + (size_t)q * D_ + h * 32 + lg * 8);
    const unsigned int* mrowp = mw + ((size_t)b * N_ + q) * NW_;

    float m = -1e30f, lsum = 0.f;
    f32x4 of[2];
    of[0] = f32x4{0.f, 0.f, 0.f, 0.f};
    of[1] = f32x4{0.f, 0.f, 0.f, 0.f};
    const f32x4 zero = {0.f, 0.f, 0.f, 0.f};
    const float sc = 0.25503330560513437f;   // 1/sqrt(32) * log2(e)
    bf16* pl = plds[wid];

    for (int ks = 0; ks < N_ / 64; ++ks) {
        int k0 = ks * 64;
        bf16x8 kf[4];
#pragma unroll
        for (int t = 0; t < 4; ++t)
            kf[t] = *(const bf16x8*)(Kt + bnD + (size_t)(k0 + t * 16 + lr) * D_ + h * 32 + lg * 8);
        unsigned int w0 = mrowp[ks * 2], w1 = mrowp[ks * 2 + 1];
        f32x4 s[4];
#pragma unroll
        for (int t = 0; t < 4; ++t)
            s[t] = mfma16(kf[t], qf, zero);   // S^T[k][q]

        // mask + scale (log2 units); lane's k = t*16 + lg*4 + r
        float sv[16];
#pragma unroll
        for (int t = 0; t < 4; ++t) {
            unsigned int w = (t < 2) ? w0 : w1;
            int base = (t & 1) * 16 + lg * 4;
#pragma unroll
            for (int r = 0; r < 4; ++r)
                sv[t * 4 + r] = ((w >> (base + r)) & 1u) ? s[t][r] * sc : -1e30f;
        }
        // tile max: tree in-register, then 2 shuffles across lg groups
        float t0 = fmaxf(sv[0], sv[1]),  t1 = fmaxf(sv[2], sv[3]);
        float t2 = fmaxf(sv[4], sv[5]),  t3 = fmaxf(sv[6], sv[7]);
        float t4 = fmaxf(sv[8], sv[9]),  t5 = fmaxf(sv[10], sv[11]);
        float t6 = fmaxf(sv[12], sv[13]), t7 = fmaxf(sv[14], sv[15]);
        float tm = fmaxf(fmaxf(fmaxf(t0, t1), fmaxf(t2, t3)),
                         fmaxf(fmaxf(t4, t5), fmaxf(t6, t7)));
        tm = fmaxf(tm, __shfl_xor(tm, 16, 64));
        tm = fmaxf(tm, __shfl_xor(tm, 32, 64));
        float mn = fmaxf(m, tm);
        float al = __builtin_amdgcn_exp2f(m - mn);
        m = mn;
#pragma unroll
        for (int i = 0; i < 16; ++i)
            sv[i] = __builtin_amdgcn_exp2f(sv[i] - mn);
        float p0 = (sv[0] + sv[1]) + (sv[2] + sv[3]);
        float p1 = (sv[4] + sv[5]) + (sv[6] + sv[7]);
        float p2 = (sv[8] + sv[9]) + (sv[10] + sv[11]);
        float p3 = (sv[12] + sv[13]) + (sv[14] + sv[15]);
        lsum = lsum * al + ((p0 + p1) + (p2 + p3));
        of[0] *= al;
        of[1] *= al;
        // P^T to LDS: lane's 4 consecutive k per tile -> bf16x4 (b64 write)
#pragma unroll
        for (int t = 0; t < 4; ++t) {
            bf16x4 pk;
            pk[0] = (bf16)sv[t * 4 + 0]; pk[1] = (bf16)sv[t * 4 + 1];
            pk[2] = (bf16)sv[t * 4 + 2]; pk[3] = (bf16)sv[t * 4 + 3];
            *(bf16x4*)(pl + lr * 72 + t * 16 + lg * 4) = pk;
        }
        // PV: O^T[d][q] accumulate, 2 chunks of 32 k
#pragma unroll
        for (int c = 0; c < 2; ++c) {
            bf16x8 pb = *(const bf16x8*)(pl + lr * 72 + c * 32 + lg * 8);
#pragma unroll
            for (int dt = 0; dt < 2; ++dt) {
                bf16x8 vfr = *(const bf16x8*)(VT + (size_t)(bh * DH_ + dt * 16 + lr) * N_ + k0 + c * 32 + lg * 8);
                of[dt] = mfma16(vfr, pb, of[dt]);
            }
        }
    }
    // total l: sum partials across lg groups (each lane owned a k-slice)
    lsum += __shfl_xor(lsum, 16, 64);
    lsum += __shfl_xor(lsum, 32, 64);
    float rdiv = 1.f / lsum;
#pragma unroll
    for (int dt = 0; dt < 2; ++dt) {
        bf16x4 ok;
#pragma unroll
        for (int r = 0; r < 4; ++r)
            ok[r] = (bf16)(of[dt][r] * rdiv);
        *(bf16x4*)(O + bnD + (size_t)q * D_ + h * 32 + dt * 16 + lg * 4) = ok;
    }
}

// ---------------- LayerNorm (optional residual add): 1 wave per row ---------
__global__ void k_ln(const float* __restrict__ x, const float* __restrict__ res,
                     const float* __restrict__ g, const float* __restrict__ bta,
                     float* __restrict__ outF, bf16* __restrict__ outB) {
    int row = blockIdx.x * 4 + (threadIdx.x >> 6);
    int lane = threadIdx.x & 63;
    const float* xr = x + (size_t)row * D_;
    float2 e = *(const float2*)(xr + lane * 2);
    if (res) {
        float2 rr = *(const float2*)(res + (size_t)row * D_ + lane * 2);
        e.x += rr.x; e.y += rr.y;
    }
    float s = e.x + e.y, sq = e.x * e.x + e.y * e.y;
#pragma unroll
    for (int m = 1; m < 64; m <<= 1) {
        s += __shfl_xor(s, m, 64);
        sq += __shfl_xor(sq, m, 64);
    }
    float mean = s * (1.f / 128.f);
    float var = sq * (1.f / 128.f) - mean * mean;
    float rstd = rsqrtf(var + 1e-5f);
    float o0 = (e.x - mean) * rstd * g[lane * 2] + bta[lane * 2];
    float o1 = (e.y - mean) * rstd * g[lane * 2 + 1] + bta[lane * 2 + 1];
    float2 of2; of2.x = o0; of2.y = o1;
    *(float2*)(outF + (size_t)row * D_ + lane * 2) = of2;
    union { bf16 hh[2]; unsigned int u; } pk;
    pk.hh[0] = (bf16)o0; pk.hh[1] = (bf16)o1;
    *(unsigned int*)(outB + (size_t)row * D_ + lane * 2) = pk.u;
}

// ---------------- final outputs: glob, gents, emask --------------------------
__global__ void k_out(const float* __restrict__ vf, const int* __restrict__ entlens,
                      float* __restrict__ out) {
    int idx = blockIdx.x * 256 + threadIdx.x;
    if (idx < 512) {
        int b = idx >> 7, d = idx & 127;
        out[idx] = vf[((size_t)b * N_ + entlens[b]) * D_ + d];
    } else if (idx < 512 + B_ * N_ * D_) {
        out[idx] = vf[idx - 512];
    } else if (idx < 512 + B_ * N_ * D_ + B_ * N_) {
        out[idx] = 1.0f;
    }
}

extern "C" void kernel_launch(void* const* d_in, const int* in_sizes, int n_in,
                              void* d_out, int out_size, void* d_ws, size_t ws_size,
                              hipStream_t stream) {
    const float* vents = (const float*)d_in[0];
    const int*   rels  = (const int*)d_in[1];
    const int*   adj   = (const int*)d_in[2];
    const int*   entl  = (const int*)d_in[3];
    const float* renc  = (const float*)d_in[4];
    const float* Wq = (const float*)d_in[5];
    const float* bq = (const float*)d_in[6];
    const float* Wk = (const float*)d_in[7];
    const float* bk = (const float*)d_in[8];
    const float* Wv = (const float*)d_in[9];
    const float* bv = (const float*)d_in[10];
    const float* Wo = (const float*)d_in[11];
    const float* bo = (const float*)d_in[12];
    const float* l1w = (const float*)d_in[13];
    const float* l1b = (const float*)d_in[14];
    const float* l2w = (const float*)d_in[15];
    const float* l2b = (const float*)d_in[16];
    const float* lng = (const float*)d_in[17];
    const float* lnb = (const float*)d_in[18];
    const float* pra = (const float*)d_in[19];

    char* w = (char*)d_ws;
    auto alloc = [&](size_t bytes) { char* r = w; w += (bytes + 255) & ~(size_t)255; return r; };
    float* vf    = (float*)alloc((size_t)M_ * D_ * 4);
    bf16*  vb    = (bf16*)alloc((size_t)M_ * D_ * 2);
    unsigned int* mw = (unsigned int*)alloc((size_t)B_ * N_ * NW_ * 4);
    bf16*  wqkvT = (bf16*)alloc((size_t)P_ * 384 * 128 * 2);
    float* bqkv  = (float*)alloc((size_t)P_ * 384 * 4);
    bf16*  woT   = (bf16*)alloc((size_t)P_ * 128 * 128 * 2);
    bf16*  l1T   = (bf16*)alloc((size_t)P_ * 512 * 128 * 2);
    bf16*  l2T   = (bf16*)alloc((size_t)P_ * 128 * 512 * 2);
    bf16*  Qb    = (bf16*)alloc((size_t)M_ * D_ * 2);
    bf16*  Kb    = (bf16*)alloc((size_t)M_ * D_ * 2);
    bf16*  VTb   = (bf16*)alloc((size_t)M_ * D_ * 2);
    bf16*  Ob    = (bf16*)alloc((size_t)M_ * D_ * 2);
    float* Oproj = (float*)alloc((size_t)M_ * D_ * 4);
    float* tf    = (float*)alloc((size_t)M_ * D_ * 4);
    bf16*  tb    = (bf16*)alloc((size_t)M_ * D_ * 2);
    bf16*  h1    = (bf16*)alloc((size_t)M_ * 512 * 2);
    float* q2    = (float*)alloc((size_t)M_ * D_ * 4);

    k_vgraph<<<(M_ * D_ + 255) / 256, 256, 0, stream>>>(vents, rels, renc, vf, vb);
    k_mask<<<(B_ * N_ * NW_ + 255) / 256, 256, 0, stream>>>(adj, mw);
    k_prep<<<(P_ * 196992 + 255) / 256, 256, 0, stream>>>(Wq, Wk, Wv, Wo, l1w, l2w,
                                                          bq, bk, bv, wqkvT, bqkv, woT, l1T, l2T);
    for (int p = 0; p < P_; ++p) {
        k_gemm<128, 2><<<dim3(M_ / 64, 384 / 64), 64, 0, stream>>>(
            vb, wqkvT + (size_t)p * 384 * 128, bqkv + p * 384, nullptr,
            nullptr, Qb, Kb, VTb, 384);
        k_attn<<<dim3(N_ / 64, B_ * H_), 256, 0, stream>>>(Qb, Kb, VTb, mw, Ob);
        k_gemm<128, 0><<<dim3(M_ / 64, 128 / 64), 64, 0, stream>>>(
            Ob, woT + (size_t)p * 128 * 128, bo + p * 128, nullptr,
            Oproj, nullptr, nullptr, nullptr, 128);
        k_ln<<<M_ / 4, 256, 0, stream>>>(Oproj, nullptr, lng + p * 128, lnb + p * 128, tf, tb);
        k_gemm<128, 1><<<dim3(M_ / 64, 512 / 64), 64, 0, stream>>>(
            tb, l1T + (size_t)p * 512 * 128, l1b + p * 512, pra + p * 512,
            nullptr, h1, nullptr, nullptr, 512);
        k_gemm<512, 0><<<dim3(M_ / 64, 128 / 64), 64, 0, stream>>>(
            h1, l2T + (size_t)p * 128 * 512, l2b + p * 128, nullptr,
            q2, nullptr, nullptr, nullptr, 128);
        k_ln<<<M_ / 4, 256, 0, stream>>>(q2, tf, lng + p * 128, lnb + p * 128, vf, vb);
    }
    k_out<<<(512 + M_ * D_ + B_ * N_ + 255) / 256, 256, 0, stream>>>(vf, entl, (float*)d_out);
}